// Round 1
// baseline (566.697 us; speedup 1.0000x reference)
//
#include <hip/hip_runtime.h>
#include <math.h>

// Problem shapes
#define SEQ  4096
#define DIM  300
#define NCLS 4

// Grid shapes (4 waves/block of 64 lanes; 8 rows per wave)
#define NB_DENSE 128   // 32 rows/block
#define NB_SC    128
#define NB_ADD   128

// Workspace layout (float offsets)
#define OFF_P1   0
#define OFF_MID  (OFF_P1 + NB_DENSE * DIM)
#define OFF_U    (OFF_MID + DIM)
#define OFF_SC   (OFF_U + DIM)
#define OFF_BMAX (OFF_SC + SEQ)
#define OFF_P2   (OFF_BMAX + NB_SC)
// total = 128*300 + 300 + 300 + 4096 + 128 + 128*300 floats  ~= 319 KB

// --------------------------------------------------------------------------
// K1: per-block partial sums of gathered embedding rows (for mean pooling).
// 128 blocks x 256 thr (4 waves); each wave accumulates 8 rows over its
// d-stripe (lane, lane+64, ..., lane+256); LDS-combine 4 waves; write partial.
__global__ __launch_bounds__(256) void k_dense_part(
        const int* __restrict__ x, const float* __restrict__ emb,
        float* __restrict__ p1) {
    __shared__ float lds[4][320];
    const int wave = threadIdx.x >> 6, lane = threadIdx.x & 63;
    float a0 = 0.f, a1 = 0.f, a2 = 0.f, a3 = 0.f, a4 = 0.f;
    const int s0 = blockIdx.x * 32 + wave * 8;
    #pragma unroll
    for (int r = 0; r < 8; ++r) {
        const float* row = emb + (size_t)x[s0 + r] * DIM;
        a0 += row[lane];
        a1 += row[lane + 64];
        a2 += row[lane + 128];
        a3 += row[lane + 192];
        if (lane < DIM - 256) a4 += row[lane + 256];
    }
    lds[wave][lane]       = a0;
    lds[wave][lane + 64]  = a1;
    lds[wave][lane + 128] = a2;
    lds[wave][lane + 192] = a3;
    lds[wave][lane + 256] = a4;   // lanes >= 44 store junk; never read (d<300)
    __syncthreads();
    for (int d = threadIdx.x; d < DIM; d += 256) {
        float s = lds[0][d] + lds[1][d] + lds[2][d] + lds[3][d];
        p1[blockIdx.x * DIM + d] = s;
    }
}

// --------------------------------------------------------------------------
// K2: dense = (sum of partials)/SEQ; mid = W1 @ dense + b1.
// 75 blocks x 256 thr; each block redundantly reduces dense into LDS (cheap,
// L2-resident), then its 4 waves compute 4 rows of mid via wave-reduce dot.
__global__ __launch_bounds__(256) void k_mid(
        const float* __restrict__ p1, const float* __restrict__ W1,
        const float* __restrict__ b1, float* __restrict__ mid) {
    __shared__ float dense[DIM];
    for (int d = threadIdx.x; d < DIM; d += 256) {
        float s = 0.f;
        for (int b = 0; b < NB_DENSE; ++b) s += p1[b * DIM + d];
        dense[d] = s * (1.0f / (float)SEQ);
    }
    __syncthreads();
    const int wave = threadIdx.x >> 6, lane = threadIdx.x & 63;
    const int i = blockIdx.x * 4 + wave;   // grid=75 -> i in [0,300)
    const float* w = W1 + (size_t)i * DIM;
    float s = w[lane] * dense[lane] + w[lane + 64] * dense[lane + 64]
            + w[lane + 128] * dense[lane + 128]
            + w[lane + 192] * dense[lane + 192];
    if (lane < DIM - 256) s += w[lane + 256] * dense[lane + 256];
    for (int off = 32; off; off >>= 1) s += __shfl_down(s, off);
    if (lane == 0) mid[i] = s + b1[i];
}

// --------------------------------------------------------------------------
// K3: u = Wb @ mid   (u[d] = sum_e Wb[d,e]*mid[e]); same structure as K2.
__global__ __launch_bounds__(256) void k_u(
        const float* __restrict__ mid, const float* __restrict__ Wb,
        float* __restrict__ u) {
    __shared__ float v[DIM];
    for (int d = threadIdx.x; d < DIM; d += 256) v[d] = mid[d];
    __syncthreads();
    const int wave = threadIdx.x >> 6, lane = threadIdx.x & 63;
    const int i = blockIdx.x * 4 + wave;
    const float* w = Wb + (size_t)i * DIM;
    float s = w[lane] * v[lane] + w[lane + 64] * v[lane + 64]
            + w[lane + 128] * v[lane + 128] + w[lane + 192] * v[lane + 192];
    if (lane < DIM - 256) s += w[lane + 256] * v[lane + 256];
    for (int off = 32; off; off >>= 1) s += __shfl_down(s, off);
    if (lane == 0) u[i] = s;
}

// --------------------------------------------------------------------------
// K4: scores[s] = embed[s] . u + bb; also per-block max for softmax.
// 128 blocks x 256 thr; each wave computes 8 scores (one wave-reduce dot each).
__global__ __launch_bounds__(256) void k_scores(
        const int* __restrict__ x, const float* __restrict__ emb,
        const float* __restrict__ u, const float* __restrict__ bb,
        float* __restrict__ sc, float* __restrict__ bmax) {
    __shared__ float lmax[4];
    const int wave = threadIdx.x >> 6, lane = threadIdx.x & 63;
    float u0 = u[lane], u1 = u[lane + 64], u2 = u[lane + 128],
          u3 = u[lane + 192];
    float u4 = (lane < DIM - 256) ? u[lane + 256] : 0.f;
    const float bbv = bb[0];
    float wmax = -1e30f;
    const int s0 = blockIdx.x * 32 + wave * 8;
    #pragma unroll
    for (int r = 0; r < 8; ++r) {
        const float* row = emb + (size_t)x[s0 + r] * DIM;
        float s = row[lane] * u0 + row[lane + 64] * u1
                + row[lane + 128] * u2 + row[lane + 192] * u3;
        if (lane < DIM - 256) s += row[lane + 256] * u4;
        for (int off = 32; off; off >>= 1) s += __shfl_down(s, off);
        if (lane == 0) {
            s += bbv;
            sc[s0 + r] = s;
            wmax = fmaxf(wmax, s);
        }
    }
    if (lane == 0) lmax[wave] = wmax;
    __syncthreads();
    if (threadIdx.x == 0)
        bmax[blockIdx.x] =
            fmaxf(fmaxf(lmax[0], lmax[1]), fmaxf(lmax[2], lmax[3]));
}

// --------------------------------------------------------------------------
// K5: softmax (each block redundantly computes global max + exp-sum — only
// 4096 expf, trivial), writes reward to d_out, accumulates partial
// reward-weighted row sums for the "addition" pooling.
__global__ __launch_bounds__(256) void k_soft_add(
        const int* __restrict__ x, const float* __restrict__ emb,
        const float* __restrict__ sc, const float* __restrict__ bmax,
        float* __restrict__ reward, float* __restrict__ p2) {
    __shared__ float red[4];
    __shared__ float lds[4][320];
    const int wave = threadIdx.x >> 6, lane = threadIdx.x & 63;
    // global max
    float m = -1e30f;
    for (int i = threadIdx.x; i < NB_SC; i += 256) m = fmaxf(m, bmax[i]);
    for (int off = 32; off; off >>= 1) m = fmaxf(m, __shfl_down(m, off));
    if (lane == 0) red[wave] = m;
    __syncthreads();
    const float mx = fmaxf(fmaxf(red[0], red[1]), fmaxf(red[2], red[3]));
    __syncthreads();
    // global exp-sum
    float s = 0.f;
    for (int i = threadIdx.x; i < SEQ; i += 256) s += expf(sc[i] - mx);
    for (int off = 32; off; off >>= 1) s += __shfl_down(s, off);
    if (lane == 0) red[wave] = s;
    __syncthreads();
    const float inv = 1.0f / (red[0] + red[1] + red[2] + red[3]);
    // weighted partial row-sum over this block's 32 rows
    float a0 = 0.f, a1 = 0.f, a2 = 0.f, a3 = 0.f, a4 = 0.f;
    const int s0 = blockIdx.x * 32 + wave * 8;
    #pragma unroll
    for (int r = 0; r < 8; ++r) {
        const int srow = s0 + r;
        const float rw = expf(sc[srow] - mx) * inv;
        if (lane == 0) reward[srow] = rw;
        const float* row = emb + (size_t)x[srow] * DIM;
        a0 += rw * row[lane];
        a1 += rw * row[lane + 64];
        a2 += rw * row[lane + 128];
        a3 += rw * row[lane + 192];
        if (lane < DIM - 256) a4 += rw * row[lane + 256];
    }
    lds[wave][lane]       = a0;
    lds[wave][lane + 64]  = a1;
    lds[wave][lane + 128] = a2;
    lds[wave][lane + 192] = a3;
    lds[wave][lane + 256] = a4;
    __syncthreads();
    for (int d = threadIdx.x; d < DIM; d += 256) {
        float t = lds[0][d] + lds[1][d] + lds[2][d] + lds[3][d];
        p2[blockIdx.x * DIM + d] = t;
    }
}

// --------------------------------------------------------------------------
// K6: addition = (sum of partials)/SEQ; out[c] = W2[c] . (mid+addition) + b2.
// Single block; 4 waves handle the 4 classes.
__global__ __launch_bounds__(256) void k_out(
        const float* __restrict__ p2, const float* __restrict__ mid,
        const float* __restrict__ W2, const float* __restrict__ b2,
        float* __restrict__ out) {
    __shared__ float v[DIM];
    for (int d = threadIdx.x; d < DIM; d += 256) {
        float s = 0.f;
        for (int b = 0; b < NB_ADD; ++b) s += p2[b * DIM + d];
        v[d] = mid[d] + s * (1.0f / (float)SEQ);
    }
    __syncthreads();
    const int wave = threadIdx.x >> 6, lane = threadIdx.x & 63;
    const float* w = W2 + (size_t)wave * DIM;   // wave in [0,4) == class
    float s = w[lane] * v[lane] + w[lane + 64] * v[lane + 64]
            + w[lane + 128] * v[lane + 128] + w[lane + 192] * v[lane + 192];
    if (lane < DIM - 256) s += w[lane + 256] * v[lane + 256];
    for (int off = 32; off; off >>= 1) s += __shfl_down(s, off);
    if (lane == 0) out[wave] = s + b2[wave];
}

// --------------------------------------------------------------------------
extern "C" void kernel_launch(void* const* d_in, const int* in_sizes, int n_in,
                              void* d_out, int out_size, void* d_ws,
                              size_t ws_size, hipStream_t stream) {
    const int*   x   = (const int*)d_in[0];
    const float* emb = (const float*)d_in[1];
    const float* W1  = (const float*)d_in[2];
    const float* b1  = (const float*)d_in[3];
    const float* Wb  = (const float*)d_in[4];
    const float* bb  = (const float*)d_in[5];
    const float* W2  = (const float*)d_in[6];
    const float* b2  = (const float*)d_in[7];
    float* out = (float*)d_out;
    float* ws  = (float*)d_ws;

    float* P1   = ws + OFF_P1;
    float* MID  = ws + OFF_MID;
    float* U    = ws + OFF_U;
    float* SC   = ws + OFF_SC;
    float* BMAX = ws + OFF_BMAX;
    float* P2   = ws + OFF_P2;

    k_dense_part<<<NB_DENSE, 256, 0, stream>>>(x, emb, P1);
    k_mid<<<75, 256, 0, stream>>>(P1, W1, b1, MID);
    k_u<<<75, 256, 0, stream>>>(MID, Wb, U);
    k_scores<<<NB_SC, 256, 0, stream>>>(x, emb, U, bb, SC, BMAX);
    k_soft_add<<<NB_ADD, 256, 0, stream>>>(x, emb, SC, BMAX, out + NCLS, P2);
    k_out<<<1, 256, 0, stream>>>(P2, MID, W2, b2, out);
}